// Round 1
// baseline (568.422 us; speedup 1.0000x reference)
//
#include <hip/hip_runtime.h>
#include <hip/hip_bf16.h>
#include <cstdint>
#include <cstddef>

#define T_TOK 8192
#define DIM   1024
#define HID   2048
#define NE    8
#define CAP   3072
#define BK    64
#define LDK   72   // BK + 8 pad elements -> 144B row stride, bank-balanced b128

typedef __attribute__((ext_vector_type(8))) short bf16x8;
typedef __attribute__((ext_vector_type(4))) float f32x4;
using bf16 = __hip_bfloat16;

// ---------------- x -> bf16 ----------------
__global__ void k_convert_x(const float* __restrict__ x, bf16* __restrict__ xb) {
    int i = (blockIdx.x * blockDim.x + threadIdx.x) * 4;
    float4 v = *(const float4*)(x + i);
    bf16 o[4] = {__float2bfloat16(v.x), __float2bfloat16(v.y),
                 __float2bfloat16(v.z), __float2bfloat16(v.w)};
    *(uint2*)(xb + i) = *(const uint2*)o;
}

// ---------- per-expert transpose + convert: in [E][R][C] f32 -> out [E][C][R] bf16 ----------
__global__ void k_transpose_bf16(const float* __restrict__ in, bf16* __restrict__ out,
                                 int R, int C) {
    __shared__ float tile[32][33];
    int e  = blockIdx.y;
    int ct = C / 32;
    int rt0 = (blockIdx.x / ct) * 32;
    int c0  = (blockIdx.x % ct) * 32;
    int tx = threadIdx.x & 31, ty = threadIdx.x >> 5;
    const float* src = in + (size_t)e * R * C;
    bf16* dst = out + (size_t)e * R * C;
#pragma unroll
    for (int i = 0; i < 4; ++i)
        tile[ty + 8 * i][tx] = src[(size_t)(rt0 + ty + 8 * i) * C + c0 + tx];
    __syncthreads();
#pragma unroll
    for (int i = 0; i < 4; ++i)
        dst[(size_t)(c0 + ty + 8 * i) * R + rt0 + tx] = __float2bfloat16(tile[tx][ty + 8 * i]);
}

// ---------------- router: logits (fp64 accum) ----------------
__global__ __launch_bounds__(256) void k_logits(const float* __restrict__ x,
                                                const float* __restrict__ Wr,
                                                float* __restrict__ logits) {
    __shared__ float wl[NE][DIM];
    for (int o = threadIdx.x; o < NE * DIM; o += 256) {
        int e = o >> 10, d = o & (DIM - 1);
        wl[e][d] = Wr[d * NE + e];
    }
    __syncthreads();
    int wid = threadIdx.x >> 6, lane = threadIdx.x & 63;
    int t = blockIdx.x * 4 + wid;
    const float* xr = x + (size_t)t * DIM;
    double acc[NE];
#pragma unroll
    for (int e = 0; e < NE; ++e) acc[e] = 0.0;
    for (int i = 0; i < DIM / 64; ++i) {
        float xv = xr[i * 64 + lane];
#pragma unroll
        for (int e = 0; e < NE; ++e)
            acc[e] += (double)xv * (double)wl[e][i * 64 + lane];
    }
#pragma unroll
    for (int e = 0; e < NE; ++e) {
        double v = acc[e];
        for (int m = 32; m >= 1; m >>= 1) v += __shfl_xor(v, m);
        if (lane == 0) logits[t * NE + e] = (float)v;
    }
}

// ---------------- router: softmax, top-2, segment append ----------------
__global__ __launch_bounds__(256) void k_route(const float* __restrict__ logits,
                                               int* counts, int* seg_tok, float* seg_w,
                                               float* probsum) {
    int t = blockIdx.x * 256 + threadIdx.x;
    float l[NE];
#pragma unroll
    for (int e = 0; e < NE; ++e) l[e] = logits[t * NE + e];
    float mx = l[0];
#pragma unroll
    for (int e = 1; e < NE; ++e) mx = fmaxf(mx, l[e]);
    float p[NE], s = 0.f;
#pragma unroll
    for (int e = 0; e < NE; ++e) { p[e] = expf(l[e] - mx); s += p[e]; }
    float inv = 1.f / s;
#pragma unroll
    for (int e = 0; e < NE; ++e) p[e] *= inv;
    // top-2, ties -> lower index (match jax.lax.top_k)
    int e0 = 0; float v0 = p[0];
#pragma unroll
    for (int e = 1; e < NE; ++e) if (p[e] > v0) { v0 = p[e]; e0 = e; }
    int e1 = -1; float v1 = -1.f;
#pragma unroll
    for (int e = 0; e < NE; ++e) if (e != e0 && p[e] > v1) { v1 = p[e]; e1 = e; }
    float wsum = v0 + v1;
    float w0 = v0 / wsum, w1 = v1 / wsum;

    int lane = threadIdx.x & 63, wid = threadIdx.x >> 6;
    __shared__ float ps[4][NE];
#pragma unroll
    for (int e = 0; e < NE; ++e) {
        float v = p[e];
        for (int m = 32; m >= 1; m >>= 1) v += __shfl_xor(v, m);
        if (lane == 0) ps[wid][e] = v;
    }
    __syncthreads();
    if (threadIdx.x < NE) {
        float v = ps[0][threadIdx.x] + ps[1][threadIdx.x] + ps[2][threadIdx.x] + ps[3][threadIdx.x];
        atomicAdd(&probsum[threadIdx.x], v);
    }
    // wave-aggregated append
    for (int slot = 0; slot < 2; ++slot) {
        int   e  = slot ? e1 : e0;
        float wv = slot ? w1 : w0;
#pragma unroll
        for (int ex = 0; ex < NE; ++ex) {
            unsigned long long m = __ballot(e == ex);
            if (e == ex) {
                int leader = __ffsll(m) - 1;
                int base = 0;
                if (lane == leader) base = atomicAdd(&counts[ex], __popcll(m));
                base = __shfl(base, leader);
                int pos = base + (int)__popcll(m & ((1ull << lane) - 1ull));
                if (pos < CAP) {
                    seg_tok[ex * CAP + pos] = t;
                    seg_w[ex * CAP + pos]  = wv;
                }
            }
        }
    }
}

// ---------------- GEMM1: h = silu(xg @ w1t^T) * (xg @ w3t^T), gathered rows ----------------
__global__ __launch_bounds__(256, 2) void k_gemm1(const bf16* __restrict__ xb,
                                                  const bf16* __restrict__ w1t,
                                                  const bf16* __restrict__ w3t,
                                                  const int* __restrict__ counts,
                                                  const int* __restrict__ seg_tok,
                                                  bf16* __restrict__ h) {
    int e = blockIdx.y;
    int cnt = counts[e]; cnt = cnt < CAP ? cnt : CAP;
    const int NT = HID / 128;                 // 16
    int mtile = blockIdx.x / NT, ntile = blockIdx.x % NT;
    if (mtile * 128 >= cnt) return;

    __shared__ __align__(16) bf16 As[128 * LDK];
    __shared__ __align__(16) bf16 Bg[128 * LDK];
    __shared__ __align__(16) bf16 Bu[128 * LDK];
    __shared__ int toks[128];
    if (threadIdx.x < 128) {
        int slot = mtile * 128 + threadIdx.x;
        toks[threadIdx.x] = seg_tok[e * CAP + (slot < cnt ? slot : 0)];
    }
    __syncthreads();

    f32x4 zero4 = {0.f, 0.f, 0.f, 0.f};
    f32x4 accg[4][4], accu[4][4];
#pragma unroll
    for (int m = 0; m < 4; ++m)
#pragma unroll
        for (int n = 0; n < 4; ++n) { accg[m][n] = zero4; accu[m][n] = zero4; }

    int lane = threadIdx.x & 63, wid = threadIdx.x >> 6;
    int wr = wid >> 1, wc = wid & 1;
    const bf16* bgsrc = w1t + (size_t)(e * HID + ntile * 128) * DIM;
    const bf16* busrc = w3t + (size_t)(e * HID + ntile * 128) * DIM;

    for (int k0 = 0; k0 < DIM; k0 += BK) {
#pragma unroll
        for (int c = 0; c < 4; ++c) {
            int ci = threadIdx.x + c * 256;
            int row = ci >> 3, off = (ci & 7) * 8;
            *(uint4*)(&As[row * LDK + off]) = *(const uint4*)(xb + (size_t)toks[row] * DIM + k0 + off);
            *(uint4*)(&Bg[row * LDK + off]) = *(const uint4*)(bgsrc + (size_t)row * DIM + k0 + off);
            *(uint4*)(&Bu[row * LDK + off]) = *(const uint4*)(busrc + (size_t)row * DIM + k0 + off);
        }
        __syncthreads();
#pragma unroll
        for (int ks = 0; ks < 2; ++ks) {
            bf16x8 af[4];
#pragma unroll
            for (int m = 0; m < 4; ++m)
                af[m] = *(const bf16x8*)(&As[(wr * 64 + m * 16 + (lane & 15)) * LDK + ks * 32 + (lane >> 4) * 8]);
#pragma unroll
            for (int n = 0; n < 4; ++n) {
                bf16x8 bg = *(const bf16x8*)(&Bg[(wc * 64 + n * 16 + (lane & 15)) * LDK + ks * 32 + (lane >> 4) * 8]);
                bf16x8 bu = *(const bf16x8*)(&Bu[(wc * 64 + n * 16 + (lane & 15)) * LDK + ks * 32 + (lane >> 4) * 8]);
#pragma unroll
                for (int m = 0; m < 4; ++m) {
                    accg[m][n] = __builtin_amdgcn_mfma_f32_16x16x32_bf16(af[m], bg, accg[m][n], 0, 0, 0);
                    accu[m][n] = __builtin_amdgcn_mfma_f32_16x16x32_bf16(af[m], bu, accu[m][n], 0, 0, 0);
                }
            }
        }
        __syncthreads();
    }
    // epilogue: silu(g)*u -> bf16 h
    bf16* hdst = h + ((size_t)e * CAP + (size_t)mtile * 128) * HID + ntile * 128;
#pragma unroll
    for (int m = 0; m < 4; ++m)
#pragma unroll
        for (int n = 0; n < 4; ++n)
#pragma unroll
            for (int r = 0; r < 4; ++r) {
                int row = wr * 64 + m * 16 + (lane >> 4) * 4 + r;
                int col = wc * 64 + n * 16 + (lane & 15);
                float g = accg[m][n][r], u = accu[m][n][r];
                float hv = g / (1.f + __expf(-g)) * u;
                hdst[(size_t)row * HID + col] = __float2bfloat16(hv);
            }
}

// ---------------- GEMM2: out[tok] += (h @ w2t^T) * w, atomic scatter ----------------
__global__ __launch_bounds__(256, 2) void k_gemm2(const bf16* __restrict__ h,
                                                  const bf16* __restrict__ w2t,
                                                  const int* __restrict__ counts,
                                                  const int* __restrict__ seg_tok,
                                                  const float* __restrict__ seg_w,
                                                  float* __restrict__ out) {
    int e = blockIdx.y;
    int cnt = counts[e]; cnt = cnt < CAP ? cnt : CAP;
    const int NT = DIM / 128;                 // 8
    int mtile = blockIdx.x / NT, ntile = blockIdx.x % NT;
    if (mtile * 128 >= cnt) return;

    __shared__ __align__(16) bf16 As[128 * LDK];
    __shared__ __align__(16) bf16 Bs[128 * LDK];
    __shared__ int   toks[128];
    __shared__ float wts[128];
    if (threadIdx.x < 128) {
        int slot = mtile * 128 + threadIdx.x;
        bool v = slot < cnt;
        toks[threadIdx.x] = v ? seg_tok[e * CAP + slot] : -1;
        wts[threadIdx.x]  = v ? seg_w[e * CAP + slot] : 0.f;
    }
    __syncthreads();

    f32x4 zero4 = {0.f, 0.f, 0.f, 0.f};
    f32x4 acc[4][4];
#pragma unroll
    for (int m = 0; m < 4; ++m)
#pragma unroll
        for (int n = 0; n < 4; ++n) acc[m][n] = zero4;

    int lane = threadIdx.x & 63, wid = threadIdx.x >> 6;
    int wr = wid >> 1, wc = wid & 1;
    const bf16* asrc = h + ((size_t)e * CAP + (size_t)mtile * 128) * HID;
    const bf16* bsrc = w2t + (size_t)(e * DIM + ntile * 128) * HID;

    for (int k0 = 0; k0 < HID; k0 += BK) {
#pragma unroll
        for (int c = 0; c < 4; ++c) {
            int ci = threadIdx.x + c * 256;
            int row = ci >> 3, off = (ci & 7) * 8;
            *(uint4*)(&As[row * LDK + off]) = *(const uint4*)(asrc + (size_t)row * HID + k0 + off);
            *(uint4*)(&Bs[row * LDK + off]) = *(const uint4*)(bsrc + (size_t)row * HID + k0 + off);
        }
        __syncthreads();
#pragma unroll
        for (int ks = 0; ks < 2; ++ks) {
            bf16x8 af[4];
#pragma unroll
            for (int m = 0; m < 4; ++m)
                af[m] = *(const bf16x8*)(&As[(wr * 64 + m * 16 + (lane & 15)) * LDK + ks * 32 + (lane >> 4) * 8]);
#pragma unroll
            for (int n = 0; n < 4; ++n) {
                bf16x8 b = *(const bf16x8*)(&Bs[(wc * 64 + n * 16 + (lane & 15)) * LDK + ks * 32 + (lane >> 4) * 8]);
#pragma unroll
                for (int m = 0; m < 4; ++m)
                    acc[m][n] = __builtin_amdgcn_mfma_f32_16x16x32_bf16(af[m], b, acc[m][n], 0, 0, 0);
            }
        }
        __syncthreads();
    }
#pragma unroll
    for (int m = 0; m < 4; ++m)
#pragma unroll
        for (int n = 0; n < 4; ++n)
#pragma unroll
            for (int r = 0; r < 4; ++r) {
                int row = wr * 64 + m * 16 + (lane >> 4) * 4 + r;
                int col = wc * 64 + n * 16 + (lane & 15);
                int tok = toks[row];
                if (tok >= 0)
                    atomicAdd(&out[(size_t)tok * DIM + ntile * 128 + col], acc[m][n][r] * wts[row]);
            }
}

// ---------------- aux loss ----------------
__global__ void k_aux(const int* __restrict__ counts, const float* __restrict__ probsum,
                      float* __restrict__ outaux) {
    if (threadIdx.x == 0 && blockIdx.x == 0) {
        float s = 0.f;
        for (int e = 0; e < NE; ++e)
            s += ((float)counts[e] / (float)T_TOK) * (probsum[e] / (float)T_TOK);
        *outaux = (float)NE * s;
    }
}

extern "C" void kernel_launch(void* const* d_in, const int* in_sizes, int n_in,
                              void* d_out, int out_size, void* d_ws, size_t ws_size,
                              hipStream_t stream) {
    const float* x  = (const float*)d_in[0];
    const float* Wr = (const float*)d_in[1];
    const float* w1 = (const float*)d_in[2];
    const float* w2 = (const float*)d_in[3];
    const float* w3 = (const float*)d_in[4];
    float* out = (float*)d_out;

    char* ws = (char*)d_ws;
    size_t off = 0;
    auto alloc = [&](size_t bytes) { void* p = ws + off; off += (bytes + 255) & ~(size_t)255; return p; };
    bf16*  xb     = (bf16*)alloc((size_t)T_TOK * DIM * 2);
    bf16*  w1t    = (bf16*)alloc((size_t)NE * HID * DIM * 2);
    bf16*  w3t    = (bf16*)alloc((size_t)NE * HID * DIM * 2);
    bf16*  w2t    = (bf16*)alloc((size_t)NE * DIM * HID * 2);
    bf16*  hbuf   = (bf16*)alloc((size_t)NE * CAP * HID * 2);
    float* logits = (float*)alloc((size_t)T_TOK * NE * 4);
    int*   counts = (int*)alloc(256);
    int*   segtok = (int*)alloc((size_t)NE * CAP * 4);
    float* segw   = (float*)alloc((size_t)NE * CAP * 4);
    float* probsum= (float*)alloc(256);
    (void)ws_size; (void)in_sizes; (void)n_in;

    hipMemsetAsync(counts, 0, 256, stream);
    hipMemsetAsync(probsum, 0, 256, stream);
    hipMemsetAsync(d_out, 0, (size_t)out_size * 4, stream);

    k_convert_x<<<T_TOK * DIM / 4 / 256, 256, 0, stream>>>(x, xb);
    dim3 gt1((DIM / 32) * (HID / 32), NE);
    k_transpose_bf16<<<gt1, 256, 0, stream>>>(w1, w1t, DIM, HID);
    k_transpose_bf16<<<gt1, 256, 0, stream>>>(w3, w3t, DIM, HID);
    dim3 gt2((HID / 32) * (DIM / 32), NE);
    k_transpose_bf16<<<gt2, 256, 0, stream>>>(w2, w2t, HID, DIM);

    k_logits<<<T_TOK / 4, 256, 0, stream>>>(x, Wr, logits);
    k_route<<<T_TOK / 256, 256, 0, stream>>>(logits, counts, segtok, segw, probsum);

    dim3 g1((CAP / 128) * (HID / 128), NE);
    k_gemm1<<<g1, 256, 0, stream>>>(xb, w1t, w3t, counts, segtok, hbuf);
    dim3 g2((CAP / 128) * (DIM / 128), NE);
    k_gemm2<<<g2, 256, 0, stream>>>(hbuf, w2t, counts, segtok, segw, out);
    k_aux<<<1, 64, 0, stream>>>(counts, probsum, out + (size_t)T_TOK * DIM);
}

// Round 2
// 439.164 us; speedup vs baseline: 1.2943x; 1.2943x over previous
//
#include <hip/hip_runtime.h>
#include <hip/hip_bf16.h>
#include <cstdint>
#include <cstddef>

#define T_TOK 8192
#define DIM   1024
#define HID   2048
#define NE    8
#define CAP   2816   // 22 tiles of 128; expected count ~2048, +18 sigma margin

typedef __attribute__((ext_vector_type(8))) short bf16x8;
typedef __attribute__((ext_vector_type(4))) float f32x4;
using bf16 = __hip_bfloat16;

__device__ __forceinline__ void gload16(const bf16* g, bf16* l) {
    __builtin_amdgcn_global_load_lds(
        (const __attribute__((address_space(1))) unsigned int*)(g),
        (__attribute__((address_space(3))) unsigned int*)(l), 16, 0, 0);
}
__device__ __forceinline__ float b2f(unsigned short u) {
    return __uint_as_float(((unsigned int)u) << 16);
}

// ---------------- x -> bf16 ----------------
__global__ void k_convert_x(const float* __restrict__ x, bf16* __restrict__ xb) {
    int i = (blockIdx.x * blockDim.x + threadIdx.x) * 4;
    float4 v = *(const float4*)(x + i);
    bf16 o[4] = {__float2bfloat16(v.x), __float2bfloat16(v.y),
                 __float2bfloat16(v.z), __float2bfloat16(v.w)};
    *(uint2*)(xb + i) = *(const uint2*)o;
}

// ---- per-expert transpose+convert: [E][R][C] f32 -> [E][C][R] bf16, 64x64 tiles ----
__global__ __launch_bounds__(256) void k_transpose_bf16(const float* __restrict__ in,
                                                        bf16* __restrict__ out, int R, int C) {
    __shared__ float tile[64][65];
    int e = blockIdx.y;
    int ct = C >> 6;
    int r0 = (blockIdx.x / ct) << 6;
    int c0 = (blockIdx.x % ct) << 6;
    const float* src = in + (size_t)e * R * C;
    bf16* dst = out + (size_t)e * R * C;
    int s = threadIdx.x & 15, g = threadIdx.x >> 4;
#pragma unroll
    for (int j = 0; j < 4; ++j) {
        int row = j * 16 + g;
        float4 v = *(const float4*)(src + (size_t)(r0 + row) * C + c0 + s * 4);
        tile[row][s * 4 + 0] = v.x; tile[row][s * 4 + 1] = v.y;
        tile[row][s * 4 + 2] = v.z; tile[row][s * 4 + 3] = v.w;
    }
    __syncthreads();
#pragma unroll
    for (int j = 0; j < 4; ++j) {
        int c = j * 16 + g;
        int r = s * 4;
        bf16 o[4] = {__float2bfloat16(tile[r][c]),     __float2bfloat16(tile[r + 1][c]),
                     __float2bfloat16(tile[r + 2][c]), __float2bfloat16(tile[r + 3][c])};
        *(uint2*)(dst + (size_t)(c0 + c) * R + r0 + r) = *(const uint2*)o;
    }
}

// ---------------- router: logits (fp64 accum) ----------------
__global__ __launch_bounds__(256) void k_logits(const float* __restrict__ x,
                                                const float* __restrict__ Wr,
                                                float* __restrict__ logits) {
    __shared__ float wl[NE][DIM];
    for (int o = threadIdx.x; o < NE * DIM; o += 256) {
        int e = o >> 10, d = o & (DIM - 1);
        wl[e][d] = Wr[d * NE + e];
    }
    __syncthreads();
    int wid = threadIdx.x >> 6, lane = threadIdx.x & 63;
    int t = blockIdx.x * 4 + wid;
    const float* xr = x + (size_t)t * DIM;
    double acc[NE];
#pragma unroll
    for (int e = 0; e < NE; ++e) acc[e] = 0.0;
    for (int i = 0; i < DIM / 64; ++i) {
        float xv = xr[i * 64 + lane];
#pragma unroll
        for (int e = 0; e < NE; ++e)
            acc[e] += (double)xv * (double)wl[e][i * 64 + lane];
    }
#pragma unroll
    for (int e = 0; e < NE; ++e) {
        double v = acc[e];
        for (int m = 32; m >= 1; m >>= 1) v += __shfl_xor(v, m);
        if (lane == 0) logits[t * NE + e] = (float)v;
    }
}

// ---------------- router: softmax, top-2, segment append ----------------
__global__ __launch_bounds__(256) void k_route(const float* __restrict__ logits,
                                               int* counts, int* seg_tok, float* seg_w,
                                               int* slotpos, float* probsum) {
    int t = blockIdx.x * 256 + threadIdx.x;
    float l[NE];
#pragma unroll
    for (int e = 0; e < NE; ++e) l[e] = logits[t * NE + e];
    float mx = l[0];
#pragma unroll
    for (int e = 1; e < NE; ++e) mx = fmaxf(mx, l[e]);
    float p[NE], s = 0.f;
#pragma unroll
    for (int e = 0; e < NE; ++e) { p[e] = expf(l[e] - mx); s += p[e]; }
    float inv = 1.f / s;
#pragma unroll
    for (int e = 0; e < NE; ++e) p[e] *= inv;
    int e0 = 0; float v0 = p[0];
#pragma unroll
    for (int e = 1; e < NE; ++e) if (p[e] > v0) { v0 = p[e]; e0 = e; }
    int e1 = -1; float v1 = -1.f;
#pragma unroll
    for (int e = 0; e < NE; ++e) if (e != e0 && p[e] > v1) { v1 = p[e]; e1 = e; }
    float wsum = v0 + v1;
    float w0 = v0 / wsum, w1 = v1 / wsum;

    int lane = threadIdx.x & 63, wid = threadIdx.x >> 6;
    __shared__ float ps[4][NE];
#pragma unroll
    for (int e = 0; e < NE; ++e) {
        float v = p[e];
        for (int m = 32; m >= 1; m >>= 1) v += __shfl_xor(v, m);
        if (lane == 0) ps[wid][e] = v;
    }
    __syncthreads();
    if (threadIdx.x < NE) {
        float v = ps[0][threadIdx.x] + ps[1][threadIdx.x] + ps[2][threadIdx.x] + ps[3][threadIdx.x];
        atomicAdd(&probsum[threadIdx.x], v);
    }
    for (int slot = 0; slot < 2; ++slot) {
        int   e  = slot ? e1 : e0;
        float wv = slot ? w1 : w0;
#pragma unroll
        for (int ex = 0; ex < NE; ++ex) {
            unsigned long long m = __ballot(e == ex);
            if (e == ex) {
                int leader = __ffsll(m) - 1;
                int base = 0;
                if (lane == leader) base = atomicAdd(&counts[ex], __popcll(m));
                base = __shfl(base, leader);
                int pos = base + (int)__popcll(m & ((1ull << lane) - 1ull));
                if (pos < CAP) {
                    seg_tok[ex * CAP + pos] = t;
                    seg_w[ex * CAP + pos]  = wv;
                    slotpos[2 * t + slot]  = ex * CAP + pos;
                } else {
                    slotpos[2 * t + slot]  = -1;
                }
            }
        }
    }
}

// ------- GEMM1: h = silu(xg @ w1t^T) * (xg @ w3t^T), m97-style staging -------
__global__ __launch_bounds__(256, 2) void k_gemm1(const bf16* __restrict__ xb,
                                                  const bf16* __restrict__ w1t,
                                                  const bf16* __restrict__ w3t,
                                                  const int* __restrict__ counts,
                                                  const int* __restrict__ seg_tok,
                                                  bf16* __restrict__ h) {
    __shared__ __align__(16) bf16 As[128 * 64];
    __shared__ __align__(16) bf16 Bg[128 * 64];
    __shared__ __align__(16) bf16 Bu[128 * 64];
    __shared__ int toks[128];
    const int NT = HID / 128;                       // 16
    int flat = blockIdx.y * gridDim.x + blockIdx.x;
    int cpx  = (gridDim.x * NE) >> 3;               // nwg % 8 == 0 by construction
    int swz  = (flat & 7) * cpx + (flat >> 3);
    int e    = swz / gridDim.x;
    int tile = swz % gridDim.x;
    int mtile = tile / NT, ntile = tile % NT;
    int cnt = counts[e]; if (cnt > CAP) cnt = CAP;
    if (mtile * 128 >= cnt) return;

    int tx = threadIdx.x;
    if (tx < 128) {
        int slot = mtile * 128 + tx;
        toks[tx] = seg_tok[e * CAP + (slot < cnt ? slot : 0)];
    }
    __syncthreads();

    int lane = tx & 63, w = tx >> 6;
    const bf16 *ap[4], *gp[4], *up[4];
    bf16 *al[4], *gl[4], *ul[4];
#pragma unroll
    for (int i = 0; i < 4; ++i) {
        int seg = w * 4 + i;
        int r = seg * 8 + (lane >> 3);
        int co = (lane & 7) * 8;
        ap[i] = xb  + (size_t)toks[r] * DIM + co;
        gp[i] = w1t + ((size_t)e * HID + ntile * 128 + r) * DIM + co;
        up[i] = w3t + ((size_t)e * HID + ntile * 128 + r) * DIM + co;
        al[i] = As + seg * 512; gl[i] = Bg + seg * 512; ul[i] = Bu + seg * 512;
    }

    f32x4 zero4 = {0.f, 0.f, 0.f, 0.f};
    f32x4 accg[4][4], accu[4][4];
#pragma unroll
    for (int m = 0; m < 4; ++m)
#pragma unroll
        for (int n = 0; n < 4; ++n) { accg[m][n] = zero4; accu[m][n] = zero4; }
    int wr = w >> 1, wc = w & 1;

    for (int k0 = 0; k0 < DIM; k0 += 64) {
#pragma unroll
        for (int i = 0; i < 4; ++i) {
            gload16(ap[i] + k0, al[i]);
            gload16(gp[i] + k0, gl[i]);
            gload16(up[i] + k0, ul[i]);
        }
        __syncthreads();
#pragma unroll
        for (int ks = 0; ks < 2; ++ks) {
            bf16x8 af[4];
#pragma unroll
            for (int m = 0; m < 4; ++m)
                af[m] = *(const bf16x8*)(As + (wr * 64 + m * 16 + (lane & 15)) * 64 + ks * 32 + (lane >> 4) * 8);
#pragma unroll
            for (int n = 0; n < 4; ++n) {
                bf16x8 bgf = *(const bf16x8*)(Bg + (wc * 64 + n * 16 + (lane & 15)) * 64 + ks * 32 + (lane >> 4) * 8);
                bf16x8 buf_ = *(const bf16x8*)(Bu + (wc * 64 + n * 16 + (lane & 15)) * 64 + ks * 32 + (lane >> 4) * 8);
#pragma unroll
                for (int m = 0; m < 4; ++m) {
                    accg[m][n] = __builtin_amdgcn_mfma_f32_16x16x32_bf16(af[m], bgf, accg[m][n], 0, 0, 0);
                    accu[m][n] = __builtin_amdgcn_mfma_f32_16x16x32_bf16(af[m], buf_, accu[m][n], 0, 0, 0);
                }
            }
        }
        __syncthreads();
    }
    bf16* hdst = h + ((size_t)e * CAP + (size_t)mtile * 128) * HID + ntile * 128;
#pragma unroll
    for (int m = 0; m < 4; ++m)
#pragma unroll
        for (int n = 0; n < 4; ++n)
#pragma unroll
            for (int r = 0; r < 4; ++r) {
                int row = wr * 64 + m * 16 + (lane >> 4) * 4 + r;
                int col = wc * 64 + n * 16 + (lane & 15);
                float gg = accg[m][n][r], uu = accu[m][n][r];
                float hv = gg / (1.f + __expf(-gg)) * uu;
                hdst[(size_t)row * HID + col] = __float2bfloat16(hv);
            }
}

// ------- GEMM2: ybuf[slot] = (h[slot] @ w2t^T) * w, dense stores, no atomics -------
__global__ __launch_bounds__(256, 2) void k_gemm2(const bf16* __restrict__ h,
                                                  const bf16* __restrict__ w2t,
                                                  const int* __restrict__ counts,
                                                  const float* __restrict__ seg_w,
                                                  bf16* __restrict__ ybuf) {
    __shared__ __align__(16) bf16 As[128 * 64];
    __shared__ __align__(16) bf16 Bs[128 * 64];
    __shared__ float wts[128];
    const int NT = DIM / 128;                       // 8
    int flat = blockIdx.y * gridDim.x + blockIdx.x;
    int cpx  = (gridDim.x * NE) >> 3;
    int swz  = (flat & 7) * cpx + (flat >> 3);
    int e    = swz / gridDim.x;
    int tile = swz % gridDim.x;
    int mtile = tile / NT, ntile = tile % NT;
    int cnt = counts[e]; if (cnt > CAP) cnt = CAP;
    if (mtile * 128 >= cnt) return;

    int tx = threadIdx.x;
    if (tx < 128) {
        int slot = mtile * 128 + tx;
        wts[tx] = (slot < cnt) ? seg_w[e * CAP + slot] : 0.f;
    }
    __syncthreads();

    int lane = tx & 63, w = tx >> 6;
    const bf16 *ap[4], *bp[4];
    bf16 *al[4], *bl[4];
#pragma unroll
    for (int i = 0; i < 4; ++i) {
        int seg = w * 4 + i;
        int r = seg * 8 + (lane >> 3);
        int co = (lane & 7) * 8;
        ap[i] = h   + ((size_t)e * CAP + mtile * 128 + r) * HID + co;
        bp[i] = w2t + ((size_t)e * DIM + ntile * 128 + r) * HID + co;
        al[i] = As + seg * 512; bl[i] = Bs + seg * 512;
    }

    f32x4 zero4 = {0.f, 0.f, 0.f, 0.f};
    f32x4 acc[4][4];
#pragma unroll
    for (int m = 0; m < 4; ++m)
#pragma unroll
        for (int n = 0; n < 4; ++n) acc[m][n] = zero4;
    int wr = w >> 1, wc = w & 1;

    for (int k0 = 0; k0 < HID; k0 += 64) {
#pragma unroll
        for (int i = 0; i < 4; ++i) {
            gload16(ap[i] + k0, al[i]);
            gload16(bp[i] + k0, bl[i]);
        }
        __syncthreads();
#pragma unroll
        for (int ks = 0; ks < 2; ++ks) {
            bf16x8 af[4];
#pragma unroll
            for (int m = 0; m < 4; ++m)
                af[m] = *(const bf16x8*)(As + (wr * 64 + m * 16 + (lane & 15)) * 64 + ks * 32 + (lane >> 4) * 8);
#pragma unroll
            for (int n = 0; n < 4; ++n) {
                bf16x8 b = *(const bf16x8*)(Bs + (wc * 64 + n * 16 + (lane & 15)) * 64 + ks * 32 + (lane >> 4) * 8);
#pragma unroll
                for (int m = 0; m < 4; ++m)
                    acc[m][n] = __builtin_amdgcn_mfma_f32_16x16x32_bf16(af[m], b, acc[m][n], 0, 0, 0);
            }
        }
        __syncthreads();
    }
    bf16* ydst = ybuf + ((size_t)e * CAP + (size_t)mtile * 128) * DIM + ntile * 128;
#pragma unroll
    for (int m = 0; m < 4; ++m)
#pragma unroll
        for (int n = 0; n < 4; ++n)
#pragma unroll
            for (int r = 0; r < 4; ++r) {
                int row = wr * 64 + m * 16 + (lane >> 4) * 4 + r;
                int col = wc * 64 + n * 16 + (lane & 15);
                ydst[(size_t)row * DIM + col] = __float2bfloat16(acc[m][n][r] * wts[row]);
            }
}

// ---------------- combine: out[t] = ybuf[slot0] + ybuf[slot1] ----------------
__global__ __launch_bounds__(256) void k_combine(const bf16* __restrict__ yb,
                                                 const int* __restrict__ slotpos,
                                                 float* __restrict__ out) {
    int t = blockIdx.x;
    int s0 = slotpos[2 * t], s1 = slotpos[2 * t + 1];
    int d = threadIdx.x * 4;
    float4 a = {0.f, 0.f, 0.f, 0.f};
    if (s0 >= 0) {
        ushort4 v = *(const ushort4*)(yb + (size_t)s0 * DIM + d);
        a.x += b2f(v.x); a.y += b2f(v.y); a.z += b2f(v.z); a.w += b2f(v.w);
    }
    if (s1 >= 0) {
        ushort4 v = *(const ushort4*)(yb + (size_t)s1 * DIM + d);
        a.x += b2f(v.x); a.y += b2f(v.y); a.z += b2f(v.z); a.w += b2f(v.w);
    }
    *(float4*)(out + (size_t)t * DIM + d) = a;
}

// ---------------- aux loss ----------------
__global__ void k_aux(const int* __restrict__ counts, const float* __restrict__ probsum,
                      float* __restrict__ outaux) {
    if (threadIdx.x == 0 && blockIdx.x == 0) {
        float s = 0.f;
        for (int e = 0; e < NE; ++e)
            s += ((float)counts[e] / (float)T_TOK) * (probsum[e] / (float)T_TOK);
        *outaux = (float)NE * s;
    }
}

extern "C" void kernel_launch(void* const* d_in, const int* in_sizes, int n_in,
                              void* d_out, int out_size, void* d_ws, size_t ws_size,
                              hipStream_t stream) {
    const float* x  = (const float*)d_in[0];
    const float* Wr = (const float*)d_in[1];
    const float* w1 = (const float*)d_in[2];
    const float* w2 = (const float*)d_in[3];
    const float* w3 = (const float*)d_in[4];
    float* out = (float*)d_out;

    char* ws = (char*)d_ws;
    size_t off = 0;
    auto alloc = [&](size_t bytes) { void* p = ws + off; off += (bytes + 255) & ~(size_t)255; return p; };
    bf16*  xb      = (bf16*)alloc((size_t)T_TOK * DIM * 2);
    bf16*  w1t     = (bf16*)alloc((size_t)NE * HID * DIM * 2);
    bf16*  w3t     = (bf16*)alloc((size_t)NE * HID * DIM * 2);
    bf16*  w2t     = (bf16*)alloc((size_t)NE * DIM * HID * 2);
    bf16*  hbuf    = (bf16*)alloc((size_t)NE * CAP * HID * 2);
    float* logits  = (float*)alloc((size_t)T_TOK * NE * 4);
    int*   counts  = (int*)alloc(256);
    int*   segtok  = (int*)alloc((size_t)NE * CAP * 4);
    float* segw    = (float*)alloc((size_t)NE * CAP * 4);
    int*   slotpos = (int*)alloc((size_t)T_TOK * 2 * 4);
    float* probsum = (float*)alloc(256);
    // ybuf reuses w1t+w3t (dead after k_gemm1): needs 46.1 MB < 67.1 MB available
    bf16*  ybuf    = w1t;
    (void)ws_size; (void)in_sizes; (void)n_in;

    hipMemsetAsync(counts, 0, 256, stream);
    hipMemsetAsync(probsum, 0, 256, stream);

    k_convert_x<<<T_TOK * DIM / 4 / 256, 256, 0, stream>>>(x, xb);
    dim3 gt1((DIM / 64) * (HID / 64), NE);
    k_transpose_bf16<<<gt1, 256, 0, stream>>>(w1, w1t, DIM, HID);
    k_transpose_bf16<<<gt1, 256, 0, stream>>>(w3, w3t, DIM, HID);
    dim3 gt2((HID / 64) * (DIM / 64), NE);
    k_transpose_bf16<<<gt2, 256, 0, stream>>>(w2, w2t, HID, DIM);

    k_logits<<<T_TOK / 4, 256, 0, stream>>>(x, Wr, logits);
    k_route<<<T_TOK / 256, 256, 0, stream>>>(logits, counts, segtok, segw, slotpos, probsum);

    dim3 g1((CAP / 128) * (HID / 128), NE);   // 352 x 8, nwg=2816 %8==0
    k_gemm1<<<g1, 256, 0, stream>>>(xb, w1t, w3t, counts, segtok, hbuf);
    dim3 g2((CAP / 128) * (DIM / 128), NE);   // 176 x 8, nwg=1408 %8==0
    k_gemm2<<<g2, 256, 0, stream>>>(hbuf, w2t, counts, segw, ybuf);

    k_combine<<<T_TOK, 256, 0, stream>>>(ybuf, slotpos, out);
    k_aux<<<1, 64, 0, stream>>>(counts, probsum, out + (size_t)T_TOK * DIM);
}